// Round 6
// baseline (432.161 us; speedup 1.0000x reference)
//
#include <hip/hip_runtime.h>
#include <hip/hip_bf16.h>
#include <stdint.h>

// Problem constants
#define Bq 1024
#define Dq 512
#define Nq 16
#define Hq 512
#define Mq (Bq*Nq)   // 16384

typedef short v8s  __attribute__((ext_vector_type(8)));
typedef float v16f __attribute__((ext_vector_type(16)));

typedef __attribute__((address_space(3))) unsigned int as3_u32;
typedef __attribute__((address_space(1))) const unsigned int as1_u32;

__device__ __forceinline__ unsigned short f2bf(float f) {
  union { float f; unsigned u; } v; v.f = f;
  return (unsigned short)((v.u + 0x7fffu + ((v.u >> 16) & 1u)) >> 16);
}

// Xb[b*16+n][d] = bf16(x[b][d][n])
__global__ void k_transpose_x(const float* __restrict__ x, unsigned short* __restrict__ xb) {
  __shared__ float lds[Dq][Nq + 1];
  const int b = blockIdx.x;
  const float* xi = x + (size_t)b * Dq * Nq;
  const int t = threadIdx.x;
  for (int p = 0; p < (Dq*Nq)/256; ++p) {
    int i = t + p*256;
    lds[i >> 4][i & (Nq-1)] = xi[i];
  }
  __syncthreads();
  unsigned short* o = xb + (size_t)b * Nq * Dq;
  for (int p = 0; p < (Dq*Nq)/256; ++p) {
    int i = t + p*256;
    o[i] = f2bf(lds[i & (Dq-1)][i >> 9]);   // i = n*512 + d
  }
}

// One dispatch for all weight transposes: z=0 -> Ws1, z=1 -> Ws2, z>=2 -> Wc1[z-2]
// out[z][c][r] = bf16(in[z][r][c]), 512x512 each
__global__ void k_transpose_w(const float* __restrict__ Ws1, const float* __restrict__ Ws2,
                              const float* __restrict__ Wc1,
                              unsigned short* __restrict__ Ws1t, unsigned short* __restrict__ Ws2t,
                              unsigned short* __restrict__ Wc1t) {
  __shared__ float tile[32][33];
  const int z = blockIdx.z;
  const float* in;
  unsigned short* out;
  if (z == 0)      { in = Ws1; out = Ws1t; }
  else if (z == 1) { in = Ws2; out = Ws2t; }
  else             { in = Wc1 + (size_t)(z-2) * 512 * 512; out = Wc1t + (size_t)(z-2) * 512 * 512; }
  const int tx = threadIdx.x, ty = threadIdx.y;  // (32,8)
  const int c0 = blockIdx.x * 32, r0 = blockIdx.y * 32;
#pragma unroll
  for (int j = 0; j < 4; ++j)
    tile[ty + j*8][tx] = in[(size_t)(r0 + ty + j*8) * 512 + c0 + tx];
  __syncthreads();
#pragma unroll
  for (int j = 0; j < 4; ++j) {
    int c = c0 + ty + j*8;   // output row (input col)
    int r = r0 + tx;         // output col (input row)
    out[(size_t)c * 512 + r] = f2bf(tile[tx][ty + j*8]);
  }
}

// ---- GEMM1/2 (unchanged R5 path, MODE 0 only) -------------------------------
template<int MODE, int BM>
__global__ __launch_bounds__(256, 2)
void k_gemm(const unsigned short* __restrict__ A,
            const unsigned short* __restrict__ Bt,
            const float* __restrict__ bias,
            void* __restrict__ out_,
            const float* __restrict__ w2,
            int permute) {
  constexpr int BN = 128, BK = 32, KD = 512;
  constexpr int NI = 2;
  constexpr int AG = BM / 16;
  constexpr int TG = AG + BN / 16;
  __shared__ __align__(16) unsigned short As[2][BM][BK];
  __shared__ __align__(16) unsigned short Bs[2][BN][BK];

  const int t = threadIdx.x;
  const int wave = t >> 6, lane = t & 63;
  const int wr = wave >> 1, wc = wave & 1;
  const int l32 = lane & 31, kh0 = lane >> 5;
  const int bm = blockIdx.x * BM, bn = blockIdx.y * BN;
  const int z = blockIdx.z;

  const unsigned short* Bz = Bt + (size_t)z * KD * 512;
  const float* biasz = bias + (size_t)z * 512;

  const int lrow = lane >> 2;
  const int lslot = lane & 3;

  auto stage = [&](int buf, int kt) {
#pragma unroll
    for (int i = wave; i < TG; i += 4) {
      const int isA = (i < AG);
      const int r0 = (isA ? i : i - AG) * 16;
      const int row = r0 + lrow;
      const int cg = lslot ^ ((row >> 1) & 3);
      const unsigned short* g = isA ? &A [(size_t)(bm + row) * KD + kt*BK + cg*8]
                                    : &Bz[(size_t)(bn + row) * KD + kt*BK + cg*8];
      as3_u32* d = isA ? (as3_u32*)&As[buf][r0][0] : (as3_u32*)&Bs[buf][r0][0];
      __builtin_amdgcn_global_load_lds((as1_u32*)g, d, 16, 0, 0);
    }
  };

  v16f acc[2][NI] = {};

  stage(0, 0);
  __syncthreads();

  for (int kt = 0; kt < KD / BK; ++kt) {
    const int cur = kt & 1;
    if (kt + 1 < KD / BK) stage(cur ^ 1, kt + 1);

    v8s af[2][2], bf[NI][2];
#pragma unroll
    for (int mi = 0; mi < 2; ++mi) {
      int ra = wr*64 + mi*32 + l32;
#pragma unroll
      for (int kh = 0; kh < 2; ++kh) {
        int c = kh*2 + kh0;
        af[mi][kh] = *(const v8s*)&As[cur][ra][(c ^ ((ra >> 1) & 3)) * 8];
      }
    }
#pragma unroll
    for (int ni = 0; ni < NI; ++ni) {
      int rb = wc*64 + ni*32 + l32;
#pragma unroll
      for (int kh = 0; kh < 2; ++kh) {
        int c = kh*2 + kh0;
        bf[ni][kh] = *(const v8s*)&Bs[cur][rb][(c ^ ((rb >> 1) & 3)) * 8];
      }
    }
#pragma unroll
    for (int kh = 0; kh < 2; ++kh)
#pragma unroll
      for (int mi = 0; mi < 2; ++mi)
#pragma unroll
        for (int ni = 0; ni < NI; ++ni)
          acc[mi][ni] = __builtin_amdgcn_mfma_f32_32x32x16_bf16(af[mi][kh], bf[ni][kh], acc[mi][ni], 0, 0, 0);
    __syncthreads();
  }

  unsigned short* O = (unsigned short*)out_;
#pragma unroll
  for (int mi = 0; mi < 2; ++mi) {
#pragma unroll
    for (int ni = 0; ni < NI; ++ni) {
      int col = bn + wc*64 + ni*32 + l32;
      float bcol = biasz[col];
#pragma unroll
      for (int reg = 0; reg < 16; ++reg) {
        int rl = (reg & 3) + 8*(reg >> 2) + 4*kh0;
        int grow = bm + wr*64 + mi*32 + rl;
        int orow = permute ? ((grow & 15) * Bq + (grow >> 4)) : grow;
        float v = acc[mi][ni][reg] + bcol;
        v = v >= 0.f ? v : 0.1f * v;
        O[(size_t)orow * 512 + col] = f2bf(v);
      }
    }
  }
}

// ---- GEMM3: A-from-LDS, B-from-global(L2) hybrid ---------------------------
// M=16384, N=512, K=512, 16 heads. Block: BM=128 x BN=256, 4 waves in 2x2,
// wave tile 64x128 (2 mi x 4 ni of 32x32x16 MFMA, acc=128 VGPRs).
// A staged in LDS (8 KB/kt, XOR-swizzled, global_load_lds w=16).
// B fragments loaded global->VGPR, prefetched one kt ahead, issued AFTER
// barrier1 so no barrier ever waits on a cold B load (drained for free at
// barrier2 ~1000 cyc later). LDS traffic/kt/CU drops 144->~40 KB (the R2-R5
// invariant wall); B comes from per-XCD L2 (z slowest grid dim -> 1-2 heads
// hot -> Wc1t slice L2-resident).
// Epilogue: FL[m][z] += sum over this wave's 128 cols of lrelu(acc+bc1)*Wc2.
__global__ __launch_bounds__(256, 2)
void k_gemm3(const unsigned short* __restrict__ A,
             const unsigned short* __restrict__ Bt,
             const float* __restrict__ bias,
             float* __restrict__ FL,
             const float* __restrict__ w2) {
  constexpr int BM = 128, BK = 32, KD = 512, NKT = KD / BK;
  __shared__ __align__(16) unsigned short As[BM][BK];   // 8 KB, single buffer

  const int t = threadIdx.x;
  const int wave = t >> 6, lane = t & 63;
  const int wrm = wave >> 1, wrn = wave & 1;   // 2x2 wave grid
  const int l32 = lane & 31, kh0 = lane >> 5;
  const int bm = blockIdx.x * BM;
  const int bn = blockIdx.y * 256;             // N-half per block
  const int z = blockIdx.z;

  const unsigned short* Bz = Bt + (size_t)z * KD * 512;
  const float* biasz = bias + (size_t)z * 512;
  const float* w2z = w2 + (size_t)z * 512;

  const int lrow = lane >> 2;
  const int lslot = lane & 3;

  auto stageA = [&](int kt) {
#pragma unroll
    for (int p = 0; p < 2; ++p) {
      const int r0 = (wave * 2 + p) * 16;
      const int row = r0 + lrow;
      const int cg = lslot ^ ((row >> 1) & 3);
      __builtin_amdgcn_global_load_lds((as1_u32*)&A[(size_t)(bm + row) * KD + kt*BK + cg*8],
                                       (as3_u32*)&As[r0][0], 16, 0, 0);
    }
  };

  auto loadB = [&](int kt, v8s bf[4][2]) {
#pragma unroll
    for (int ni = 0; ni < 4; ++ni) {
      const size_t rb = (size_t)(bn + wrn*128 + ni*32 + l32) * KD + kt*BK;
#pragma unroll
      for (int kh = 0; kh < 2; ++kh)
        bf[ni][kh] = *(const v8s*)&Bz[rb + (kh*2 + kh0)*8];
    }
  };

  v16f acc[2][4] = {};
  v8s bfc[4][2], bfn[4][2];

  loadB(0, bfc);
  stageA(0);

  auto body = [&](int kt, v8s bcur[4][2], v8s bnxt[4][2]) {
    __syncthreads();                       // A(kt) ready (drains only A-stage)
    v8s af[2][2];
#pragma unroll
    for (int mi = 0; mi < 2; ++mi) {
      int ra = wrm*64 + mi*32 + l32;
#pragma unroll
      for (int kh = 0; kh < 2; ++kh) {
        int c = kh*2 + kh0;
        af[mi][kh] = *(const v8s*)&As[ra][(c ^ ((ra >> 1) & 3)) * 8];
      }
    }
    if (kt + 1 < NKT) loadB(kt + 1, bnxt); // in-flight across the MFMA chain
#pragma unroll
    for (int kh = 0; kh < 2; ++kh)
#pragma unroll
      for (int mi = 0; mi < 2; ++mi)
#pragma unroll
        for (int ni = 0; ni < 4; ++ni)
          acc[mi][ni] = __builtin_amdgcn_mfma_f32_32x32x16_bf16(af[mi][kh], bcur[ni][kh], acc[mi][ni], 0, 0, 0);
    __syncthreads();                       // As free; B(kt+1) long arrived
    if (kt + 1 < NKT) stageA(kt + 1);
  };

#pragma unroll 1
  for (int kt = 0; kt < NKT; kt += 2) {
    body(kt, bfc, bfn);
    body(kt + 1, bfn, bfc);
  }

  // epilogue: partial H-reduction into FL[m][z]
#pragma unroll
  for (int mi = 0; mi < 2; ++mi) {
#pragma unroll
    for (int reg = 0; reg < 16; ++reg) {
      int rl = (reg & 3) + 8*(reg >> 2) + 4*kh0;
      float s = 0.f;
#pragma unroll
      for (int ni = 0; ni < 4; ++ni) {
        int col = bn + wrn*128 + ni*32 + l32;
        float v = acc[mi][ni][reg] + biasz[col];
        v = v >= 0.f ? v : 0.1f * v;
        s += v * w2z[col];
      }
#pragma unroll
      for (int off = 1; off < 32; off <<= 1)
        s += __shfl_xor(s, off, 64);
      if (l32 == 0) {
        int grow = bm + wrm*64 + mi*32 + rl;
        atomicAdd(&FL[(size_t)grow * Nq + z], s);
      }
    }
  }
}

// full_out[m][n] = FL[m][n] + bc2[n]; out[b][n] = sigmoid(full_out[n*B+b][n])
__global__ void k_final(const float* __restrict__ fl, const float* __restrict__ bc2,
                        float* __restrict__ out) {
  int i = blockIdx.x * 256 + threadIdx.x;   // i over Mq*Nq
  int m = i >> 4, n = i & 15;
  float v = fl[i] + bc2[n];
  out[Mq + i] = v;                           // full_out, offset by |out| = 16384
  if (n == (m >> 10)) {                      // diagonal: m = n*B + b
    int b = m & (Bq - 1);
    out[b * Nq + n] = 1.f / (1.f + __expf(-v));
  }
}

extern "C" void kernel_launch(void* const* d_in, const int* in_sizes, int n_in,
                              void* d_out, int out_size, void* d_ws, size_t ws_size,
                              hipStream_t stream) {
  (void)in_sizes; (void)n_in; (void)out_size; (void)ws_size;
  const float* x   = (const float*)d_in[0];
  const float* Ws1 = (const float*)d_in[1];
  const float* bs1 = (const float*)d_in[2];
  const float* Ws2 = (const float*)d_in[3];
  const float* bs2 = (const float*)d_in[4];
  const float* Wc1 = (const float*)d_in[5];
  const float* bc1 = (const float*)d_in[6];
  const float* Wc2 = (const float*)d_in[7];
  const float* bc2 = (const float*)d_in[8];

  char* ws = (char*)d_ws;
  unsigned short* Xb   = (unsigned short*)(ws);                          // 16 MB
  unsigned short* Hbuf = (unsigned short*)(ws + (size_t)16*1024*1024);   // 16 MB
  unsigned short* Sm   = (unsigned short*)(ws + (size_t)32*1024*1024);   // 16 MB
  unsigned short* Ws1t = (unsigned short*)(ws + (size_t)48*1024*1024);   // 512 KB
  unsigned short* Ws2t = (unsigned short*)(ws + (size_t)48*1024*1024 + 512*1024);
  unsigned short* Wc1t = (unsigned short*)(ws + (size_t)49*1024*1024);   // 8 MB
  float*          FL   = (float*)         (ws + (size_t)57*1024*1024);   // 1 MB

  hipMemsetAsync(FL, 0, (size_t)Mq * Nq * sizeof(float), stream);

  k_transpose_x<<<Bq, 256, 0, stream>>>(x, Xb);
  k_transpose_w<<<dim3(16,16,18), dim3(32,8), 0, stream>>>(Ws1, Ws2, Wc1, Ws1t, Ws2t, Wc1t);

  // shared MLP: H = lrelu(Xb@Ws1+bs1); Sm = lrelu(H@Ws2+bs2) in m = n*B+b row order
  k_gemm<0,128><<<dim3(128,4,1), 256, 0, stream>>>(Xb,   Ws1t, bs1, Hbuf, nullptr, 0);
  k_gemm<0,128><<<dim3(128,4,1), 256, 0, stream>>>(Hbuf, Ws2t, bs2, Sm,   nullptr, 1);
  // fused per-head GEMM + H-reduction into FL (A-LDS / B-global hybrid)
  k_gemm3<<<dim3(128,2,16), 256, 0, stream>>>(Sm, Wc1t, bc1, FL, Wc2);

  k_final<<<(Mq*Nq)/256, 256, 0, stream>>>(FL, bc2, (float*)d_out);
}

// Round 7
// 385.332 us; speedup vs baseline: 1.1215x; 1.1215x over previous
//
#include <hip/hip_runtime.h>
#include <hip/hip_bf16.h>
#include <stdint.h>

// Problem constants
#define Bq 1024
#define Dq 512
#define Nq 16
#define Hq 512
#define Mq (Bq*Nq)   // 16384

typedef short v8s  __attribute__((ext_vector_type(8)));
typedef float v16f __attribute__((ext_vector_type(16)));

typedef __attribute__((address_space(3))) unsigned int as3_u32;
typedef __attribute__((address_space(1))) const unsigned int as1_u32;

__device__ __forceinline__ unsigned short f2bf(float f) {
  union { float f; unsigned u; } v; v.f = f;
  return (unsigned short)((v.u + 0x7fffu + ((v.u >> 16) & 1u)) >> 16);
}

// Xb[b*16+n][d] = bf16(x[b][d][n])
__global__ void k_transpose_x(const float* __restrict__ x, unsigned short* __restrict__ xb) {
  __shared__ float lds[Dq][Nq + 1];
  const int b = blockIdx.x;
  const float* xi = x + (size_t)b * Dq * Nq;
  const int t = threadIdx.x;
  for (int p = 0; p < (Dq*Nq)/256; ++p) {
    int i = t + p*256;
    lds[i >> 4][i & (Nq-1)] = xi[i];
  }
  __syncthreads();
  unsigned short* o = xb + (size_t)b * Nq * Dq;
  for (int p = 0; p < (Dq*Nq)/256; ++p) {
    int i = t + p*256;
    o[i] = f2bf(lds[i & (Dq-1)][i >> 9]);   // i = n*512 + d
  }
}

// One dispatch for all weight transposes: z=0 -> Ws1, z=1 -> Ws2, z>=2 -> Wc1[z-2]
// out[z][c][r] = bf16(in[z][r][c]), 512x512 each
__global__ void k_transpose_w(const float* __restrict__ Ws1, const float* __restrict__ Ws2,
                              const float* __restrict__ Wc1,
                              unsigned short* __restrict__ Ws1t, unsigned short* __restrict__ Ws2t,
                              unsigned short* __restrict__ Wc1t) {
  __shared__ float tile[32][33];
  const int z = blockIdx.z;
  const float* in;
  unsigned short* out;
  if (z == 0)      { in = Ws1; out = Ws1t; }
  else if (z == 1) { in = Ws2; out = Ws2t; }
  else             { in = Wc1 + (size_t)(z-2) * 512 * 512; out = Wc1t + (size_t)(z-2) * 512 * 512; }
  const int tx = threadIdx.x, ty = threadIdx.y;  // (32,8)
  const int c0 = blockIdx.x * 32, r0 = blockIdx.y * 32;
#pragma unroll
  for (int j = 0; j < 4; ++j)
    tile[ty + j*8][tx] = in[(size_t)(r0 + ty + j*8) * 512 + c0 + tx];
  __syncthreads();
#pragma unroll
  for (int j = 0; j < 4; ++j) {
    int c = c0 + ty + j*8;   // output row (input col)
    int r = r0 + tx;         // output col (input row)
    out[(size_t)c * 512 + r] = f2bf(tile[tx][ty + j*8]);
  }
}

// 128x128 tile MFMA GEMM, BK=128 (4 K-iterations, 32 MFMA/wave per barrier pair —
// amortizes the vmcnt(0) barrier drain that pinned BK=32 variants at MfmaUtil 26%).
// Single-buffered LDS 64 KB/block -> 2 blocks/CU (dbuf at this BK would drop to 1:
// the m132 trap). A,B staged via global_load_lds w=16.
// Swizzle (256 B rows, 16 slots of 16 B): chunk c of row r at slot c ^ ((r>>1)&7);
// glds writes are HW-sequential (conflict-free); fragment reads hit each 4-bank
// granule exactly 8x per wave -> conflict-free. Fragment chunk for kstep ks:
// c = ks*2 + (lane>>5).
// Waves 2x2, wave tile 64x64 (2mi x 2ni of v_mfma_f32_32x32x16_bf16, acc 64 VGPR).
// MODE 0: out = lrelu(A@B+bias) bf16, rows permuted to m=(r&15)*1024+(r>>4) if permute.
// MODE 1: per-head z: atomicAdd FL[m][z] += sum_cols lrelu(A@B+bc1[z])*Wc2[z][col].
template<int MODE>
__global__ __launch_bounds__(256, 2)
void k_gemm(const unsigned short* __restrict__ A,
            const unsigned short* __restrict__ Bt,
            const float* __restrict__ bias,
            void* __restrict__ out_,
            const float* __restrict__ w2,
            int permute) {
  constexpr int BM = 128, BN = 128, BK = 128, KD = 512, NKT = KD / BK;
  __shared__ __align__(16) unsigned short As[BM][BK];   // 32 KB
  __shared__ __align__(16) unsigned short Bs[BN][BK];   // 32 KB

  const int t = threadIdx.x;
  const int wave = t >> 6, lane = t & 63;
  const int wrm = wave >> 1, wrn = wave & 1;
  const int l32 = lane & 31, kh0 = lane >> 5;
  const int bm = blockIdx.x * BM, bn = blockIdx.y * BN;
  const int z = blockIdx.z;

  const unsigned short* Bz = Bt + (size_t)z * KD * 512;
  const float* biasz = bias + (size_t)z * 512;

  const int srow = lane >> 4;          // 0..3 row within a 4-row glds group
  const int sslot = lane & 15;

  auto stage = [&](int kt) {
#pragma unroll
    for (int j = 0; j < 16; ++j) {
      const int g = wave * 16 + j;     // glds group: 64 total, 4 rows each
      const bool isA = (g < 32);
      const int r0 = (isA ? g : g - 32) * 4;
      const int row = r0 + srow;
      const int cg = sslot ^ ((row >> 1) & 7);
      const unsigned short* gp = isA ? &A [(size_t)(bm + row) * KD + kt*BK + cg*8]
                                     : &Bz[(size_t)(bn + row) * KD + kt*BK + cg*8];
      as3_u32* d = isA ? (as3_u32*)&As[r0][0] : (as3_u32*)&Bs[r0][0];
      __builtin_amdgcn_global_load_lds((as1_u32*)gp, d, 16, 0, 0);
    }
  };

  v16f acc[2][2] = {};

  stage(0);

  for (int kt = 0; kt < NKT; ++kt) {
    __syncthreads();                    // A/B(kt) ready
    const int ra0 = wrm*64 + l32, rb0 = wrn*64 + l32;
#pragma unroll
    for (int ks = 0; ks < 8; ++ks) {
      v8s af[2], bf[2];
#pragma unroll
      for (int mi = 0; mi < 2; ++mi) {
        int ra = ra0 + mi*32;
        af[mi] = *(const v8s*)&As[ra][(((ks*2 + kh0) ^ ((ra >> 1) & 7))) * 8];
      }
#pragma unroll
      for (int ni = 0; ni < 2; ++ni) {
        int rb = rb0 + ni*32;
        bf[ni] = *(const v8s*)&Bs[rb][(((ks*2 + kh0) ^ ((rb >> 1) & 7))) * 8];
      }
#pragma unroll
      for (int mi = 0; mi < 2; ++mi)
#pragma unroll
        for (int ni = 0; ni < 2; ++ni)
          acc[mi][ni] = __builtin_amdgcn_mfma_f32_32x32x16_bf16(af[mi], bf[ni], acc[mi][ni], 0, 0, 0);
    }
    __syncthreads();                    // As/Bs free for next stage
    if (kt + 1 < NKT) stage(kt + 1);
  }

  if (MODE == 0) {
    unsigned short* O = (unsigned short*)out_;
#pragma unroll
    for (int mi = 0; mi < 2; ++mi) {
#pragma unroll
      for (int ni = 0; ni < 2; ++ni) {
        int col = bn + wrn*64 + ni*32 + l32;
        float bcol = biasz[col];
#pragma unroll
        for (int reg = 0; reg < 16; ++reg) {
          int rl = (reg & 3) + 8*(reg >> 2) + 4*kh0;
          int grow = bm + wrm*64 + mi*32 + rl;
          int orow = permute ? ((grow & 15) * Bq + (grow >> 4)) : grow;
          float v = acc[mi][ni][reg] + bcol;
          v = v >= 0.f ? v : 0.1f * v;
          O[(size_t)orow * 512 + col] = f2bf(v);
        }
      }
    }
  } else {
    float* FL = (float*)out_;             // [Mq][Nq]
    const float* w2z = w2 + (size_t)z * 512;
#pragma unroll
    for (int mi = 0; mi < 2; ++mi) {
#pragma unroll
      for (int reg = 0; reg < 16; ++reg) {
        int rl = (reg & 3) + 8*(reg >> 2) + 4*kh0;
        float s = 0.f;
#pragma unroll
        for (int ni = 0; ni < 2; ++ni) {
          int col = bn + wrn*64 + ni*32 + l32;
          float v = acc[mi][ni][reg] + biasz[col];
          v = v >= 0.f ? v : 0.1f * v;
          s += v * w2z[col];
        }
        // reduce 32 cols within each 32-lane half (rows differ across halves)
#pragma unroll
        for (int off = 1; off < 32; off <<= 1)
          s += __shfl_xor(s, off, 64);
        if (l32 == 0) {
          int grow = bm + wrm*64 + mi*32 + rl;
          atomicAdd(&FL[(size_t)grow * Nq + z], s);
        }
      }
    }
  }
}

// full_out[m][n] = FL[m][n] + bc2[n]; out[b][n] = sigmoid(full_out[n*B+b][n])
__global__ void k_final(const float* __restrict__ fl, const float* __restrict__ bc2,
                        float* __restrict__ out) {
  int i = blockIdx.x * 256 + threadIdx.x;   // i over Mq*Nq
  int m = i >> 4, n = i & 15;
  float v = fl[i] + bc2[n];
  out[Mq + i] = v;                           // full_out, offset by |out| = 16384
  if (n == (m >> 10)) {                      // diagonal: m = n*B + b
    int b = m & (Bq - 1);
    out[b * Nq + n] = 1.f / (1.f + __expf(-v));
  }
}

extern "C" void kernel_launch(void* const* d_in, const int* in_sizes, int n_in,
                              void* d_out, int out_size, void* d_ws, size_t ws_size,
                              hipStream_t stream) {
  (void)in_sizes; (void)n_in; (void)out_size; (void)ws_size;
  const float* x   = (const float*)d_in[0];
  const float* Ws1 = (const float*)d_in[1];
  const float* bs1 = (const float*)d_in[2];
  const float* Ws2 = (const float*)d_in[3];
  const float* bs2 = (const float*)d_in[4];
  const float* Wc1 = (const float*)d_in[5];
  const float* bc1 = (const float*)d_in[6];
  const float* Wc2 = (const float*)d_in[7];
  const float* bc2 = (const float*)d_in[8];

  char* ws = (char*)d_ws;
  unsigned short* Xb   = (unsigned short*)(ws);                          // 16 MB
  unsigned short* Hbuf = (unsigned short*)(ws + (size_t)16*1024*1024);   // 16 MB
  unsigned short* Sm   = (unsigned short*)(ws + (size_t)32*1024*1024);   // 16 MB
  unsigned short* Ws1t = (unsigned short*)(ws + (size_t)48*1024*1024);   // 512 KB
  unsigned short* Ws2t = (unsigned short*)(ws + (size_t)48*1024*1024 + 512*1024);
  unsigned short* Wc1t = (unsigned short*)(ws + (size_t)49*1024*1024);   // 8 MB
  float*          FL   = (float*)         (ws + (size_t)57*1024*1024);   // 1 MB

  hipMemsetAsync(FL, 0, (size_t)Mq * Nq * sizeof(float), stream);

  k_transpose_x<<<Bq, 256, 0, stream>>>(x, Xb);
  k_transpose_w<<<dim3(16,16,18), dim3(32,8), 0, stream>>>(Ws1, Ws2, Wc1, Ws1t, Ws2t, Wc1t);

  // shared MLP: H = lrelu(Xb@Ws1+bs1); Sm = lrelu(H@Ws2+bs2) in m = n*B+b row order
  k_gemm<0><<<dim3(128,4,1), 256, 0, stream>>>(Xb,   Ws1t, bs1, Hbuf, nullptr, 0);
  k_gemm<0><<<dim3(128,4,1), 256, 0, stream>>>(Hbuf, Ws2t, bs2, Sm,   nullptr, 1);
  // fused per-head GEMM + H-reduction into FL
  k_gemm<1><<<dim3(128,4,16), 256, 0, stream>>>(Sm, Wc1t, bc1, FL, Wc2, 0);

  k_final<<<(Mq*Nq)/256, 256, 0, stream>>>(FL, bc2, (float*)d_out);
}